// Round 1
// baseline (3006.630 us; speedup 1.0000x reference)
//
#include <hip/hip_runtime.h>
#include <hip/hip_bf16.h>

// ---------------------------------------------------------------------------
// SPN layer: agg[row] += softmax(hop_coef)[d-1] * x[col]  (edge scatter)
//            h  = x + agg                                  (GIN, eps=0)
//            h1 = relu(BN(h @ W1 + b1))
//            out= relu(BN(h1 @ W2 + b2))
// BN is training-mode batch norm: per-column batch mean + biased variance.
// ---------------------------------------------------------------------------

__global__ void hop_softmax_k(const float* __restrict__ hc, float* __restrict__ hw, int K) {
    if (threadIdx.x == 0) {
        float tmp[16];
        float m = -1e30f;
        for (int k = 0; k < K; ++k) m = fmaxf(m, hc[k]);
        float s = 0.f;
        for (int k = 0; k < K; ++k) { float e = __expf(hc[k] - m); tmp[k] = e; s += e; }
        float inv = 1.f / s;
        for (int k = 0; k < K; ++k) hw[k] = tmp[k] * inv;
    }
}

// One edge handled by 32 lanes (float4 per lane). 204.8M hardware f32 atomics.
__global__ __launch_bounds__(256) void scatter_k(const float4* __restrict__ x,
        const int* __restrict__ rows, const int* __restrict__ cols,
        const int* __restrict__ ew, const float* __restrict__ hw,
        float* __restrict__ agg, int E, int K) {
    int gid = blockIdx.x * 256 + threadIdx.x;
    int e = gid >> 5;
    if (e >= E) return;
    int c4 = gid & 31;
    int d = ew[e];
    float w = (d >= 1 && d <= K) ? hw[d - 1] : 0.f;
    float4 v = x[(size_t)cols[e] * 32 + c4];
    float* dst = agg + (size_t)rows[e] * 128 + c4 * 4;
    unsafeAtomicAdd(dst + 0, w * v.x);
    unsafeAtomicAdd(dst + 1, w * v.y);
    unsafeAtomicAdd(dst + 2, w * v.z);
    unsafeAtomicAdd(dst + 3, w * v.w);
}

// Fused GEMM + bias + column-stats. Block: 64 rows x 128 cols, 256 threads,
// thread tile 8x4. K split in two 64-halves so LDS stays <= 51.2 KB
// (Wl 64x132 f32 = 33.8KB + hl 64x68 f32 = 17.4KB) -> 3 blocks/CU by LDS.
// AFFINE_IN: apply previous layer's BN scale/shift + relu while staging A.
template<bool AFFINE_IN>
__global__ __launch_bounds__(256) void gemm_bn_k(const float4* __restrict__ hin,
        const float4* __restrict__ Wg, const float* __restrict__ bias,
        const float* __restrict__ scale_in, const float* __restrict__ shift_in,
        float4* __restrict__ zout, float* __restrict__ sum_out, float* __restrict__ sq_out,
        int N) {
    __shared__ float Wl[64 * 132];
    __shared__ float hl[64 * 68];
    int tid = threadIdx.x;
    int ct = tid & 31, rt = tid >> 5;
    int c0 = ct * 4, r0 = rt * 8;
    int rblk = blockIdx.x * 64;

    float acc[8][4];
#pragma unroll
    for (int i = 0; i < 8; i++)
#pragma unroll
        for (int j = 0; j < 4; j++) acc[i][j] = 0.f;

    const float4* sc4 = (const float4*)scale_in;
    const float4* sh4 = (const float4*)shift_in;

    for (int kh = 0; kh < 2; ++kh) {
        __syncthreads();
        // stage W rows [kh*64, kh*64+64) : 64x128 fp32, padded stride 132
        for (int i = tid; i < 2048; i += 256) {
            int k = i >> 5, c4 = i & 31;
            *(float4*)&Wl[k * 132 + c4 * 4] = Wg[(size_t)(kh * 64 + k) * 32 + c4];
        }
        // stage h cols [kh*64, kh*64+64) for 64 rows, padded stride 68
        for (int i = tid; i < 1024; i += 256) {
            int r = i >> 4, c4 = i & 15;
            int gr = rblk + r;
            float4 v = make_float4(0.f, 0.f, 0.f, 0.f);
            if (gr < N) {
                v = hin[(size_t)gr * 32 + kh * 16 + c4];
                if (AFFINE_IN) {
                    float4 s = sc4[kh * 16 + c4];
                    float4 t = sh4[kh * 16 + c4];
                    v.x = fmaxf(fmaf(v.x, s.x, t.x), 0.f);
                    v.y = fmaxf(fmaf(v.y, s.y, t.y), 0.f);
                    v.z = fmaxf(fmaf(v.z, s.z, t.z), 0.f);
                    v.w = fmaxf(fmaf(v.w, s.w, t.w), 0.f);
                }
            }
            *(float4*)&hl[r * 68 + c4 * 4] = v;
        }
        __syncthreads();
        for (int k0 = 0; k0 < 64; k0 += 4) {
            float4 w0 = *(const float4*)&Wl[(k0 + 0) * 132 + c0];
            float4 w1 = *(const float4*)&Wl[(k0 + 1) * 132 + c0];
            float4 w2 = *(const float4*)&Wl[(k0 + 2) * 132 + c0];
            float4 w3 = *(const float4*)&Wl[(k0 + 3) * 132 + c0];
#pragma unroll
            for (int i = 0; i < 8; i++) {
                float4 h = *(const float4*)&hl[(r0 + i) * 68 + k0];
                acc[i][0] = fmaf(h.x, w0.x, acc[i][0]);
                acc[i][0] = fmaf(h.y, w1.x, acc[i][0]);
                acc[i][0] = fmaf(h.z, w2.x, acc[i][0]);
                acc[i][0] = fmaf(h.w, w3.x, acc[i][0]);
                acc[i][1] = fmaf(h.x, w0.y, acc[i][1]);
                acc[i][1] = fmaf(h.y, w1.y, acc[i][1]);
                acc[i][1] = fmaf(h.z, w2.y, acc[i][1]);
                acc[i][1] = fmaf(h.w, w3.y, acc[i][1]);
                acc[i][2] = fmaf(h.x, w0.z, acc[i][2]);
                acc[i][2] = fmaf(h.y, w1.z, acc[i][2]);
                acc[i][2] = fmaf(h.z, w2.z, acc[i][2]);
                acc[i][2] = fmaf(h.w, w3.z, acc[i][2]);
                acc[i][3] = fmaf(h.x, w0.w, acc[i][3]);
                acc[i][3] = fmaf(h.y, w1.w, acc[i][3]);
                acc[i][3] = fmaf(h.z, w2.w, acc[i][3]);
                acc[i][3] = fmaf(h.w, w3.w, acc[i][3]);
            }
        }
    }

    // epilogue: bias, store z, per-column partial stats
    float4 bj = *(const float4*)&bias[c0];
    float s0 = 0, s1 = 0, s2 = 0, s3 = 0, q0 = 0, q1 = 0, q2 = 0, q3 = 0;
#pragma unroll
    for (int i = 0; i < 8; i++) {
        int gr = rblk + r0 + i;
        if (gr < N) {
            float4 z;
            z.x = acc[i][0] + bj.x;
            z.y = acc[i][1] + bj.y;
            z.z = acc[i][2] + bj.z;
            z.w = acc[i][3] + bj.w;
            zout[(size_t)gr * 32 + ct] = z;
            s0 += z.x; s1 += z.y; s2 += z.z; s3 += z.w;
            q0 += z.x * z.x; q1 += z.y * z.y; q2 += z.z * z.z; q3 += z.w * z.w;
        }
    }

    // block-level reduction of stats (alias hl; all compute done, sync first)
    __syncthreads();
    float* red = hl; // need 2048 floats, hl has 4352
    red[rt * 128 + c0 + 0] = s0;
    red[rt * 128 + c0 + 1] = s1;
    red[rt * 128 + c0 + 2] = s2;
    red[rt * 128 + c0 + 3] = s3;
    red[1024 + rt * 128 + c0 + 0] = q0;
    red[1024 + rt * 128 + c0 + 1] = q1;
    red[1024 + rt * 128 + c0 + 2] = q2;
    red[1024 + rt * 128 + c0 + 3] = q3;
    __syncthreads();
    if (tid < 128) {
        float s = 0, q = 0;
#pragma unroll
        for (int rg = 0; rg < 8; rg++) {
            s += red[rg * 128 + tid];
            q += red[1024 + rg * 128 + tid];
        }
        unsafeAtomicAdd(&sum_out[tid], s);
        unsafeAtomicAdd(&sq_out[tid], q);
    }
}

__global__ void bn_fin_k(const float* __restrict__ sum, const float* __restrict__ sq,
        const float* __restrict__ gamma, const float* __restrict__ beta,
        float* __restrict__ scale, float* __restrict__ shift, float invN) {
    int c = threadIdx.x;
    float mean = sum[c] * invN;
    float var = fmaxf(sq[c] * invN - mean * mean, 0.f);
    float sc = gamma[c] * rsqrtf(var + 1e-5f);
    scale[c] = sc;
    shift[c] = beta[c] - mean * sc;
}

__global__ __launch_bounds__(256) void apply_k(float4* __restrict__ z,
        const float4* __restrict__ scale, const float4* __restrict__ shift, int n4) {
    int gid = blockIdx.x * 256 + threadIdx.x;
    if (gid >= n4) return;
    int c4 = gid & 31;
    float4 v = z[gid], s = scale[c4], t = shift[c4];
    v.x = fmaxf(fmaf(v.x, s.x, t.x), 0.f);
    v.y = fmaxf(fmaf(v.y, s.y, t.y), 0.f);
    v.z = fmaxf(fmaf(v.z, s.z, t.z), 0.f);
    v.w = fmaxf(fmaf(v.w, s.w, t.w), 0.f);
    z[gid] = v;
}

extern "C" void kernel_launch(void* const* d_in, const int* in_sizes, int n_in,
                              void* d_out, int out_size, void* d_ws, size_t ws_size,
                              hipStream_t stream) {
    const float* x   = (const float*)d_in[0];
    const int*   ei  = (const int*)d_in[1];
    const int*   ew  = (const int*)d_in[2];
    const float* hc  = (const float*)d_in[3];
    const float* W1  = (const float*)d_in[4];
    const float* b1  = (const float*)d_in[5];
    const float* g1  = (const float*)d_in[6];
    const float* be1 = (const float*)d_in[7];
    const float* W2  = (const float*)d_in[8];
    const float* b2  = (const float*)d_in[9];
    const float* g2  = (const float*)d_in[10];
    const float* be2 = (const float*)d_in[11];

    int N = in_sizes[0] / 128;
    int E = in_sizes[2];
    int K = in_sizes[3];

    float* ws  = (float*)d_ws;
    float* agg = ws;                              // N*128: becomes h = x + agg
    float* z1  = ws + (size_t)N * 128;            // N*128: pre-BN layer-1 output
    float* aux = ws + (size_t)2 * N * 128;
    float* hw     = aux;          // 8
    float* sum1   = aux + 8;      // 128
    float* sq1    = aux + 136;    // 128
    float* sum2   = aux + 264;    // 128
    float* sq2    = aux + 392;    // 128
    float* scale1 = aux + 520;    // 128
    float* shift1 = aux + 648;    // 128
    float* scale2 = aux + 776;    // 128
    float* shift2 = aux + 904;    // 128

    // zero the 4 stat accumulators (512 floats)
    hipMemsetAsync(sum1, 0, 512 * sizeof(float), stream);
    // agg starts as x, so GIN combine (1+eps)*x + agg is free (eps = 0)
    hipMemcpyAsync(agg, x, (size_t)N * 128 * sizeof(float), hipMemcpyDeviceToDevice, stream);

    hop_softmax_k<<<1, 64, 0, stream>>>(hc, hw, K);

    {
        long long tot = (long long)E * 32;
        int blocks = (int)((tot + 255) / 256);
        scatter_k<<<blocks, 256, 0, stream>>>((const float4*)x, ei, ei + E, ew, hw, agg, E, K);
    }

    int gblocks = (N + 63) / 64;
    gemm_bn_k<false><<<gblocks, 256, 0, stream>>>((const float4*)agg, (const float4*)W1, b1,
        nullptr, nullptr, (float4*)z1, sum1, sq1, N);
    bn_fin_k<<<1, 128, 0, stream>>>(sum1, sq1, g1, be1, scale1, shift1, 1.0f / (float)N);
    gemm_bn_k<true><<<gblocks, 256, 0, stream>>>((const float4*)z1, (const float4*)W2, b2,
        scale1, shift1, (float4*)d_out, sum2, sq2, N);
    bn_fin_k<<<1, 128, 0, stream>>>(sum2, sq2, g2, be2, scale2, shift2, 1.0f / (float)N);

    {
        int n4 = N * 32;
        apply_k<<<(n4 + 255) / 256, 256, 0, stream>>>((float4*)d_out,
            (const float4*)scale2, (const float4*)shift2, n4);
    }
}

// Round 2
// 625.419 us; speedup vs baseline: 4.8074x; 4.8074x over previous
//
#include <hip/hip_runtime.h>
#include <hip/hip_bf16.h>

// ---------------------------------------------------------------------------
// SPN layer: agg[row] += softmax(hop_coef)[d-1] * x[col]  (edge scatter)
//            h  = x + agg                                  (GIN, eps=0)
//            h1 = relu(BN(h @ W1 + b1))
//            out= relu(BN(h1 @ W2 + b2))
//
// R2: replaced f32 atomic scatter (204.8M atomics -> 3.2GB TCC beats, 2.68ms)
// with per-call CSR build (int atomics only) + pull-style gather (0 atomics).
// ---------------------------------------------------------------------------

__global__ void hop_softmax_k(const float* __restrict__ hc, float* __restrict__ hw, int K) {
    if (threadIdx.x == 0) {
        float tmp[16];
        float m = -1e30f;
        for (int k = 0; k < K; ++k) m = fmaxf(m, hc[k]);
        float s = 0.f;
        for (int k = 0; k < K; ++k) { float e = __expf(hc[k] - m); tmp[k] = e; s += e; }
        float inv = 1.f / s;
        for (int k = 0; k < K; ++k) hw[k] = tmp[k] * inv;
    }
}

// --- CSR build ---------------------------------------------------------------

__global__ __launch_bounds__(256) void count_k(const int* __restrict__ rows,
        int* __restrict__ cnt, int E) {
    int e = blockIdx.x * 256 + threadIdx.x;
    if (e < E) atomicAdd(&cnt[rows[e]], 1);
}

// per-block inclusive scan of counts; writes block-local EXCLUSIVE prefix + block sum
__global__ __launch_bounds__(256) void scan1_k(const int* __restrict__ cnt,
        int* __restrict__ s1, int* __restrict__ bsum, int N) {
    __shared__ int lds[256];
    int t = threadIdx.x;
    int i = blockIdx.x * 256 + t;
    int v = (i < N) ? cnt[i] : 0;
    lds[t] = v;
    __syncthreads();
#pragma unroll
    for (int off = 1; off < 256; off <<= 1) {
        int a = lds[t];
        int b = (t >= off) ? lds[t - off] : 0;
        __syncthreads();
        lds[t] = a + b;
        __syncthreads();
    }
    if (i < N) s1[i] = lds[t] - v;           // exclusive within block
    if (t == 255) bsum[blockIdx.x] = lds[255];
}

// single-block exclusive scan of the block sums (NB <= 512)
__global__ __launch_bounds__(512) void scan2_k(const int* __restrict__ bsum,
        int* __restrict__ bscan, int NB) {
    __shared__ int lds[512];
    int t = threadIdx.x;
    int v = (t < NB) ? bsum[t] : 0;
    lds[t] = v;
    __syncthreads();
#pragma unroll
    for (int off = 1; off < 512; off <<= 1) {
        int a = lds[t];
        int b = (t >= off) ? lds[t - off] : 0;
        __syncthreads();
        lds[t] = a + b;
        __syncthreads();
    }
    if (t < NB) bscan[t] = lds[t] - v;       // exclusive
}

// slot edges into CSR order: (col, w_e) per slot. cur[] pre-zeroed.
__global__ __launch_bounds__(256) void fill_k(const int* __restrict__ rows,
        const int* __restrict__ cols, const int* __restrict__ ew,
        const float* __restrict__ hw, const int* __restrict__ s1,
        const int* __restrict__ bscan, int* __restrict__ cur,
        int* __restrict__ ecol, float* __restrict__ eww, int E, int K) {
    int e = blockIdx.x * 256 + threadIdx.x;
    if (e >= E) return;
    int r = rows[e];
    int d = ew[e];
    float w = (d >= 1 && d <= K) ? hw[d - 1] : 0.f;
    int base = s1[r] + bscan[r >> 8];
    int pos = base + atomicAdd(&cur[r], 1);
    ecol[pos] = cols[e];
    eww[pos] = w;
}

// --- pull gather: one wave per destination row; h = x[row] + sum w*x[col] ----
__global__ __launch_bounds__(256) void gather_k(const float2* __restrict__ x2,
        const int* __restrict__ ecol, const float* __restrict__ eww,
        const int* __restrict__ s1, const int* __restrict__ bscan,
        const int* __restrict__ cnt, float2* __restrict__ h2, int N) {
    int wid = (blockIdx.x * 256 + threadIdx.x) >> 6;
    if (wid >= N) return;
    int lane = threadIdx.x & 63;
    int start = s1[wid] + bscan[wid >> 8];
    int deg = cnt[wid];
    float2 acc = x2[(size_t)wid * 64 + lane];      // GIN self term (eps = 0)
    for (int j0 = 0; j0 < deg; j0 += 64) {
        int m = min(64, deg - j0);
        int cm = 0; float wm = 0.f;
        if (lane < m) {
            cm = ecol[start + j0 + lane];
            wm = eww[start + j0 + lane];
        }
        for (int j = 0; j < m; ++j) {
            int c = __shfl(cm, j);
            float w = __shfl(wm, j);
            float2 v = x2[(size_t)c * 64 + lane];   // 512B coalesced per wave
            acc.x = fmaf(w, v.x, acc.x);
            acc.y = fmaf(w, v.y, acc.y);
        }
    }
    h2[(size_t)wid * 64 + lane] = acc;
}

// --- fused GEMM + bias + column stats (unchanged from R1) --------------------
template<bool AFFINE_IN>
__global__ __launch_bounds__(256) void gemm_bn_k(const float4* __restrict__ hin,
        const float4* __restrict__ Wg, const float* __restrict__ bias,
        const float* __restrict__ scale_in, const float* __restrict__ shift_in,
        float4* __restrict__ zout, float* __restrict__ sum_out, float* __restrict__ sq_out,
        int N) {
    __shared__ float Wl[64 * 132];
    __shared__ float hl[64 * 68];
    int tid = threadIdx.x;
    int ct = tid & 31, rt = tid >> 5;
    int c0 = ct * 4, r0 = rt * 8;
    int rblk = blockIdx.x * 64;

    float acc[8][4];
#pragma unroll
    for (int i = 0; i < 8; i++)
#pragma unroll
        for (int j = 0; j < 4; j++) acc[i][j] = 0.f;

    const float4* sc4 = (const float4*)scale_in;
    const float4* sh4 = (const float4*)shift_in;

    for (int kh = 0; kh < 2; ++kh) {
        __syncthreads();
        for (int i = tid; i < 2048; i += 256) {
            int k = i >> 5, c4 = i & 31;
            *(float4*)&Wl[k * 132 + c4 * 4] = Wg[(size_t)(kh * 64 + k) * 32 + c4];
        }
        for (int i = tid; i < 1024; i += 256) {
            int r = i >> 4, c4 = i & 15;
            int gr = rblk + r;
            float4 v = make_float4(0.f, 0.f, 0.f, 0.f);
            if (gr < N) {
                v = hin[(size_t)gr * 32 + kh * 16 + c4];
                if (AFFINE_IN) {
                    float4 s = sc4[kh * 16 + c4];
                    float4 t = sh4[kh * 16 + c4];
                    v.x = fmaxf(fmaf(v.x, s.x, t.x), 0.f);
                    v.y = fmaxf(fmaf(v.y, s.y, t.y), 0.f);
                    v.z = fmaxf(fmaf(v.z, s.z, t.z), 0.f);
                    v.w = fmaxf(fmaf(v.w, s.w, t.w), 0.f);
                }
            }
            *(float4*)&hl[r * 68 + c4 * 4] = v;
        }
        __syncthreads();
        for (int k0 = 0; k0 < 64; k0 += 4) {
            float4 w0 = *(const float4*)&Wl[(k0 + 0) * 132 + c0];
            float4 w1 = *(const float4*)&Wl[(k0 + 1) * 132 + c0];
            float4 w2 = *(const float4*)&Wl[(k0 + 2) * 132 + c0];
            float4 w3 = *(const float4*)&Wl[(k0 + 3) * 132 + c0];
#pragma unroll
            for (int i = 0; i < 8; i++) {
                float4 h = *(const float4*)&hl[(r0 + i) * 68 + k0];
                acc[i][0] = fmaf(h.x, w0.x, acc[i][0]);
                acc[i][0] = fmaf(h.y, w1.x, acc[i][0]);
                acc[i][0] = fmaf(h.z, w2.x, acc[i][0]);
                acc[i][0] = fmaf(h.w, w3.x, acc[i][0]);
                acc[i][1] = fmaf(h.x, w0.y, acc[i][1]);
                acc[i][1] = fmaf(h.y, w1.y, acc[i][1]);
                acc[i][1] = fmaf(h.z, w2.y, acc[i][1]);
                acc[i][1] = fmaf(h.w, w3.y, acc[i][1]);
                acc[i][2] = fmaf(h.x, w0.z, acc[i][2]);
                acc[i][2] = fmaf(h.y, w1.z, acc[i][2]);
                acc[i][2] = fmaf(h.z, w2.z, acc[i][2]);
                acc[i][2] = fmaf(h.w, w3.z, acc[i][2]);
                acc[i][3] = fmaf(h.x, w0.w, acc[i][3]);
                acc[i][3] = fmaf(h.y, w1.w, acc[i][3]);
                acc[i][3] = fmaf(h.z, w2.w, acc[i][3]);
                acc[i][3] = fmaf(h.w, w3.w, acc[i][3]);
            }
        }
    }

    float4 bj = *(const float4*)&bias[c0];
    float s0 = 0, s1v = 0, s2 = 0, s3 = 0, q0 = 0, q1 = 0, q2 = 0, q3 = 0;
#pragma unroll
    for (int i = 0; i < 8; i++) {
        int gr = rblk + r0 + i;
        if (gr < N) {
            float4 z;
            z.x = acc[i][0] + bj.x;
            z.y = acc[i][1] + bj.y;
            z.z = acc[i][2] + bj.z;
            z.w = acc[i][3] + bj.w;
            zout[(size_t)gr * 32 + ct] = z;
            s0 += z.x; s1v += z.y; s2 += z.z; s3 += z.w;
            q0 += z.x * z.x; q1 += z.y * z.y; q2 += z.z * z.z; q3 += z.w * z.w;
        }
    }

    __syncthreads();
    float* red = hl;
    red[rt * 128 + c0 + 0] = s0;
    red[rt * 128 + c0 + 1] = s1v;
    red[rt * 128 + c0 + 2] = s2;
    red[rt * 128 + c0 + 3] = s3;
    red[1024 + rt * 128 + c0 + 0] = q0;
    red[1024 + rt * 128 + c0 + 1] = q1;
    red[1024 + rt * 128 + c0 + 2] = q2;
    red[1024 + rt * 128 + c0 + 3] = q3;
    __syncthreads();
    if (tid < 128) {
        float s = 0, q = 0;
#pragma unroll
        for (int rg = 0; rg < 8; rg++) {
            s += red[rg * 128 + tid];
            q += red[1024 + rg * 128 + tid];
        }
        unsafeAtomicAdd(&sum_out[tid], s);
        unsafeAtomicAdd(&sq_out[tid], q);
    }
}

__global__ void bn_fin_k(const float* __restrict__ sum, const float* __restrict__ sq,
        const float* __restrict__ gamma, const float* __restrict__ beta,
        float* __restrict__ scale, float* __restrict__ shift, float invN) {
    int c = threadIdx.x;
    float mean = sum[c] * invN;
    float var = fmaxf(sq[c] * invN - mean * mean, 0.f);
    float sc = gamma[c] * rsqrtf(var + 1e-5f);
    scale[c] = sc;
    shift[c] = beta[c] - mean * sc;
}

__global__ __launch_bounds__(256) void apply_k(float4* __restrict__ z,
        const float4* __restrict__ scale, const float4* __restrict__ shift, int n4) {
    int gid = blockIdx.x * 256 + threadIdx.x;
    if (gid >= n4) return;
    int c4 = gid & 31;
    float4 v = z[gid], s = scale[c4], t = shift[c4];
    v.x = fmaxf(fmaf(v.x, s.x, t.x), 0.f);
    v.y = fmaxf(fmaf(v.y, s.y, t.y), 0.f);
    v.z = fmaxf(fmaf(v.z, s.z, t.z), 0.f);
    v.w = fmaxf(fmaf(v.w, s.w, t.w), 0.f);
    z[gid] = v;
}

extern "C" void kernel_launch(void* const* d_in, const int* in_sizes, int n_in,
                              void* d_out, int out_size, void* d_ws, size_t ws_size,
                              hipStream_t stream) {
    const float* x   = (const float*)d_in[0];
    const int*   ei  = (const int*)d_in[1];
    const int*   ew  = (const int*)d_in[2];
    const float* hc  = (const float*)d_in[3];
    const float* W1  = (const float*)d_in[4];
    const float* b1  = (const float*)d_in[5];
    const float* g1  = (const float*)d_in[6];
    const float* be1 = (const float*)d_in[7];
    const float* W2  = (const float*)d_in[8];
    const float* b2  = (const float*)d_in[9];
    const float* g2  = (const float*)d_in[10];
    const float* be2 = (const float*)d_in[11];

    int N = in_sizes[0] / 128;
    int E = in_sizes[2];
    int K = in_sizes[3];
    int NB = (N + 255) / 256;

    float* ws = (float*)d_ws;
    float* h   = ws;                               // N*128
    float* z1  = ws + (size_t)N * 128;             // N*128
    int*   cnt = (int*)(ws + (size_t)2 * N * 128); // N
    int*   cur = cnt + N;                          // N (contiguous w/ cnt for one memset)
    int*   s1  = cur + N;                          // N
    int*   bscan = s1 + N;                         // 512
    int*   bsum  = bscan + 512;                    // 512
    int*   ecol  = bsum + 512;                     // E
    float* eww   = (float*)(ecol + E);             // E
    float* aux   = eww + E;
    float* hw     = aux;          // 8
    float* sum1   = aux + 8;      // 128
    float* sq1    = aux + 136;    // 128
    float* sum2   = aux + 264;    // 128
    float* sq2    = aux + 392;    // 128
    float* scale1 = aux + 520;    // 128
    float* shift1 = aux + 648;    // 128
    float* scale2 = aux + 776;    // 128
    float* shift2 = aux + 904;    // 128

    hipMemsetAsync(cnt, 0, (size_t)2 * N * sizeof(int), stream);   // cnt + cur
    hipMemsetAsync(sum1, 0, 512 * sizeof(float), stream);          // BN stat accumulators

    hop_softmax_k<<<1, 64, 0, stream>>>(hc, hw, K);

    int eblocks = (E + 255) / 256;
    count_k<<<eblocks, 256, 0, stream>>>(ei, cnt, E);
    scan1_k<<<NB, 256, 0, stream>>>(cnt, s1, bsum, N);
    scan2_k<<<1, 512, 0, stream>>>(bsum, bscan, NB);
    fill_k<<<eblocks, 256, 0, stream>>>(ei, ei + E, ew, hw, s1, bscan, cur, ecol, eww, E, K);

    {
        long long tot = (long long)N * 64;
        int blocks = (int)((tot + 255) / 256);
        gather_k<<<blocks, 256, 0, stream>>>((const float2*)x, ecol, eww, s1, bscan, cnt,
                                             (float2*)h, N);
    }

    int gblocks = (N + 63) / 64;
    gemm_bn_k<false><<<gblocks, 256, 0, stream>>>((const float4*)h, (const float4*)W1, b1,
        nullptr, nullptr, (float4*)z1, sum1, sq1, N);
    bn_fin_k<<<1, 128, 0, stream>>>(sum1, sq1, g1, be1, scale1, shift1, 1.0f / (float)N);
    gemm_bn_k<true><<<gblocks, 256, 0, stream>>>((const float4*)z1, (const float4*)W2, b2,
        scale1, shift1, (float4*)d_out, sum2, sq2, N);
    bn_fin_k<<<1, 128, 0, stream>>>(sum2, sq2, g2, be2, scale2, shift2, 1.0f / (float)N);

    {
        int n4 = N * 32;
        apply_k<<<(n4 + 255) / 256, 256, 0, stream>>>((float4*)d_out,
            (const float4*)scale2, (const float4*)shift2, n4);
    }
}

// Round 3
// 574.187 us; speedup vs baseline: 5.2363x; 1.0892x over previous
//
#include <hip/hip_runtime.h>
#include <hip/hip_bf16.h>

// ---------------------------------------------------------------------------
// SPN layer (R3): CSR build (packed col|d) -> bf16 gather -> split-bf16 MFMA
// GEMMs (hi/lo residual, 3-term ~= fp32 accuracy) -> BN -> relu.
// ---------------------------------------------------------------------------

typedef __attribute__((ext_vector_type(8))) short short8;
typedef __attribute__((ext_vector_type(4))) float f32x4;

__device__ inline unsigned short f2bf(float v) {           // RNE bf16 round
    unsigned int u = __float_as_uint(v);
    unsigned int r = (u + 0x7fffu + ((u >> 16) & 1u)) >> 16;
    return (unsigned short)r;
}
__device__ inline float bf2f(unsigned short u) {
    return __uint_as_float(((unsigned int)u) << 16);
}

__global__ void hop_softmax_k(const float* __restrict__ hc, float* __restrict__ hwp, int K) {
    if (threadIdx.x == 0) {
        float tmp[8];
        float m = -1e30f;
        for (int k = 0; k < K; ++k) m = fmaxf(m, hc[k]);
        float s = 0.f;
        for (int k = 0; k < K; ++k) { float e = __expf(hc[k] - m); tmp[k] = e; s += e; }
        float inv = 1.f / s;
        for (int k = 0; k < 8; ++k) hwp[k] = 0.f;
        for (int k = 0; k < K; ++k) hwp[k + 1] = tmp[k] * inv;  // hwp[d], d=1..K; hwp[0]=0
    }
}

// x fp32 -> bf16 (gather payload)
__global__ __launch_bounds__(256) void xsplit_k(const float4* __restrict__ x4,
        uint4* __restrict__ xb, long long n8) {
    long long g = (long long)blockIdx.x * 256 + threadIdx.x;
    if (g >= n8) return;
    float4 a = x4[g * 2], b = x4[g * 2 + 1];
    union { unsigned short us[8]; uint4 v; } o;
    o.us[0] = f2bf(a.x); o.us[1] = f2bf(a.y); o.us[2] = f2bf(a.z); o.us[3] = f2bf(a.w);
    o.us[4] = f2bf(b.x); o.us[5] = f2bf(b.y); o.us[6] = f2bf(b.z); o.us[7] = f2bf(b.w);
    xb[g] = o.v;
}

// W [k][n] fp32 -> transposed split Wt_hi/Wt_lo [n][k] bf16
__global__ __launch_bounds__(256) void wsplit_k(const float* __restrict__ W1,
        const float* __restrict__ W2, unsigned short* __restrict__ w1h,
        unsigned short* __restrict__ w1l, unsigned short* __restrict__ w2h,
        unsigned short* __restrict__ w2l) {
    const float* W = blockIdx.x ? W2 : W1;
    unsigned short* th = blockIdx.x ? w2h : w1h;
    unsigned short* tl = blockIdx.x ? w2l : w1l;
    for (int i = threadIdx.x; i < 16384; i += 256) {
        int k = i >> 7, n = i & 127;
        float v = W[k * 128 + n];
        unsigned short hi = f2bf(v);
        th[n * 128 + k] = hi;
        tl[n * 128 + k] = f2bf(v - bf2f(hi));
    }
}

// --- CSR build ---------------------------------------------------------------
__global__ __launch_bounds__(256) void count_k(const int* __restrict__ rows,
        int* __restrict__ cnt, int E) {
    int e = blockIdx.x * 256 + threadIdx.x;
    if (e < E) atomicAdd(&cnt[rows[e]], 1);
}

__global__ __launch_bounds__(256) void scan1_k(const int* __restrict__ cnt,
        int* __restrict__ s1, int* __restrict__ bsum, int N) {
    __shared__ int lds[256];
    int t = threadIdx.x;
    int i = blockIdx.x * 256 + t;
    int v = (i < N) ? cnt[i] : 0;
    lds[t] = v;
    __syncthreads();
#pragma unroll
    for (int off = 1; off < 256; off <<= 1) {
        int a = lds[t];
        int b = (t >= off) ? lds[t - off] : 0;
        __syncthreads();
        lds[t] = a + b;
        __syncthreads();
    }
    if (i < N) s1[i] = lds[t] - v;
    if (t == 255) bsum[blockIdx.x] = lds[255];
}

__global__ __launch_bounds__(512) void scan2_k(const int* __restrict__ bsum,
        int* __restrict__ bscan, int NB) {
    __shared__ int lds[512];
    int t = threadIdx.x;
    int v = (t < NB) ? bsum[t] : 0;
    lds[t] = v;
    __syncthreads();
#pragma unroll
    for (int off = 1; off < 512; off <<= 1) {
        int a = lds[t];
        int b = (t >= off) ? lds[t - off] : 0;
        __syncthreads();
        lds[t] = a + b;
        __syncthreads();
    }
    if (t < NB) bscan[t] = lds[t] - v;
}

// pack (col, d) -> one int per CSR slot
__global__ __launch_bounds__(256) void fill_k(const int* __restrict__ rows,
        const int* __restrict__ cols, const int* __restrict__ ew,
        const int* __restrict__ s1, const int* __restrict__ bscan,
        int* __restrict__ cur, int* __restrict__ ecol, int E, int K) {
    int e = blockIdx.x * 256 + threadIdx.x;
    if (e >= E) return;
    int r = rows[e];
    int d = ew[e];
    if (d < 1 || d > K) d = 0;                 // hwp[0] = 0 -> weight 0
    int base = s1[r] + bscan[r >> 8];
    int pos = base + atomicAdd(&cur[r], 1);
    ecol[pos] = cols[e] | (d << 24);
}

// one wave per row: h = x[row] + sum_j w_j * xb[col_j]; write h as bf16 hi/lo
__global__ __launch_bounds__(256) void gather_k(const float2* __restrict__ x2,
        const unsigned int* __restrict__ xb,  // bf16 x as uint (2 elems/lane)
        const int* __restrict__ ecol, const float* __restrict__ hwp,
        const int* __restrict__ s1, const int* __restrict__ bscan,
        const int* __restrict__ cnt, unsigned int* __restrict__ hhi2,
        unsigned int* __restrict__ hlo2, int N) {
    int wid = (blockIdx.x * 256 + threadIdx.x) >> 6;
    if (wid >= N) return;
    int lane = threadIdx.x & 63;
    float hwreg = (lane < 8) ? hwp[lane] : 0.f;
    int start = s1[wid] + bscan[wid >> 8];
    int deg = cnt[wid];
    float2 acc = x2[(size_t)wid * 64 + lane];          // GIN self term (eps=0)
    for (int j0 = 0; j0 < deg; j0 += 64) {
        int m = min(64, deg - j0);
        int pm = 0;
        if (lane < m) pm = ecol[start + j0 + lane];
        for (int j = 0; j < m; ++j) {
            int pk = __shfl(pm, j);
            int c = pk & 0xFFFFFF;
            float w = __shfl(hwreg, pk >> 24);
            unsigned int u = xb[(size_t)c * 64 + lane];  // 2 bf16, 256B/row/wave
            acc.x = fmaf(w, bf2f((unsigned short)(u & 0xFFFF)), acc.x);
            acc.y = fmaf(w, bf2f((unsigned short)(u >> 16)), acc.y);
        }
    }
    unsigned short hx = f2bf(acc.x), hy = f2bf(acc.y);
    hhi2[(size_t)wid * 64 + lane] = (unsigned int)hx | ((unsigned int)hy << 16);
    unsigned short lx = f2bf(acc.x - bf2f(hx)), ly = f2bf(acc.y - bf2f(hy));
    hlo2[(size_t)wid * 64 + lane] = (unsigned int)lx | ((unsigned int)ly << 16);
}

// --- split-bf16 MFMA GEMM + bias + column stats ------------------------------
// Block: 128 rows x 128 cols, 256 threads (4 waves, 32 rows each).
// W (transposed, split) staged in LDS (68KB); A fragments loaded directly from
// global (each h-row used by exactly one block -> no reuse -> no LDS for A).
// AFFINE: A = relu(scale*z1 + shift) computed in registers, split to hi/lo.
template<bool AFFINE>
__global__ __launch_bounds__(256) void gemm_mfma_k(
        const unsigned short* __restrict__ Ahi, const unsigned short* __restrict__ Alo,
        const float* __restrict__ Az,
        const unsigned short* __restrict__ Bhg, const unsigned short* __restrict__ Blg,
        const float* __restrict__ bias,
        const float* __restrict__ scale_in, const float* __restrict__ shift_in,
        float* __restrict__ zout, float* __restrict__ sum_out, float* __restrict__ sq_out,
        int N) {
    __shared__ unsigned short Bh[128 * 136];
    __shared__ unsigned short Bl[128 * 136];
    int tid = threadIdx.x;
    // stage W^T hi/lo into LDS, 16B chunks
    for (int i = tid; i < 4096; i += 256) {
        int half = i >> 11;
        int j = i & 2047;
        int n = j >> 4, c = j & 15;
        const uint4* src = (const uint4*)((half ? Blg : Bhg) + n * 128 + c * 8);
        uint4* dst = (uint4*)((half ? Bl : Bh) + n * 136 + c * 8);
        *dst = *src;
    }
    __syncthreads();

    int wave = tid >> 6, lane = tid & 63;
    int n16 = lane & 15, q = lane >> 4;
    int rowbase = blockIdx.x * 128 + wave * 32;

    f32x4 acc[2][8];
#pragma unroll
    for (int mt = 0; mt < 2; mt++)
#pragma unroll
        for (int t = 0; t < 8; t++) acc[mt][t] = (f32x4){0.f, 0.f, 0.f, 0.f};

    int ldsb = n16 * 136 + q * 8;

#pragma unroll
    for (int k0 = 0; k0 < 128; k0 += 32) {
        short8 ahi[2], alo[2];
#pragma unroll
        for (int mt = 0; mt < 2; mt++) {
            int ar = rowbase + mt * 16 + n16;
            ar = min(ar, N - 1);
            size_t off = (size_t)ar * 128 + k0 + q * 8;
            if (!AFFINE) {
                ahi[mt] = *(const short8*)(Ahi + off);
                alo[mt] = *(const short8*)(Alo + off);
            } else {
                const float4* zp = (const float4*)(Az + off);
                float4 z0 = zp[0], z1 = zp[1];
                const float4* sp = (const float4*)(scale_in + k0 + q * 8);
                const float4* tp = (const float4*)(shift_in + k0 + q * 8);
                float4 s0 = sp[0], s1 = sp[1], t0 = tp[0], t1 = tp[1];
                float v[8];
                v[0] = fmaxf(fmaf(z0.x, s0.x, t0.x), 0.f);
                v[1] = fmaxf(fmaf(z0.y, s0.y, t0.y), 0.f);
                v[2] = fmaxf(fmaf(z0.z, s0.z, t0.z), 0.f);
                v[3] = fmaxf(fmaf(z0.w, s0.w, t0.w), 0.f);
                v[4] = fmaxf(fmaf(z1.x, s1.x, t1.x), 0.f);
                v[5] = fmaxf(fmaf(z1.y, s1.y, t1.y), 0.f);
                v[6] = fmaxf(fmaf(z1.z, s1.z, t1.z), 0.f);
                v[7] = fmaxf(fmaf(z1.w, s1.w, t1.w), 0.f);
#pragma unroll
                for (int e = 0; e < 8; e++) {
                    unsigned short hb = f2bf(v[e]);
                    ahi[mt][e] = (short)hb;
                    alo[mt][e] = (short)f2bf(v[e] - bf2f(hb));
                }
            }
        }
#pragma unroll
        for (int t = 0; t < 8; t++) {
            short8 bhi = *(const short8*)&Bh[t * 16 * 136 + ldsb + k0];
            short8 blo = *(const short8*)&Bl[t * 16 * 136 + ldsb + k0];
#pragma unroll
            for (int mt = 0; mt < 2; mt++) {
                acc[mt][t] = __builtin_amdgcn_mfma_f32_16x16x32_bf16(ahi[mt], bhi, acc[mt][t], 0, 0, 0);
                acc[mt][t] = __builtin_amdgcn_mfma_f32_16x16x32_bf16(alo[mt], bhi, acc[mt][t], 0, 0, 0);
                acc[mt][t] = __builtin_amdgcn_mfma_f32_16x16x32_bf16(ahi[mt], blo, acc[mt][t], 0, 0, 0);
            }
        }
    }

    // epilogue: bias, store, per-column stats
    float csum[8], csq[8];
#pragma unroll
    for (int t = 0; t < 8; t++) { csum[t] = 0.f; csq[t] = 0.f; }
#pragma unroll
    for (int t = 0; t < 8; t++) {
        int col = n16 + 16 * t;
        float bv = bias[col];
#pragma unroll
        for (int mt = 0; mt < 2; mt++) {
#pragma unroll
            for (int r = 0; r < 4; r++) {
                int row = rowbase + mt * 16 + q * 4 + r;
                if (row < N) {
                    float v = acc[mt][t][r] + bv;
                    zout[(size_t)row * 128 + col] = v;
                    csum[t] += v;
                    csq[t] += v * v;
                }
            }
        }
    }
    // wave reduce over rows (cols preserved: lanes xor 16/32 share lane&15)
#pragma unroll
    for (int t = 0; t < 8; t++) {
        csum[t] += __shfl_xor(csum[t], 16);
        csum[t] += __shfl_xor(csum[t], 32);
        csq[t] += __shfl_xor(csq[t], 16);
        csq[t] += __shfl_xor(csq[t], 32);
    }
    __syncthreads();                 // all MFMA LDS reads done; reuse Bh
    float* red = (float*)Bh;
    if (q == 0) {
#pragma unroll
        for (int t = 0; t < 8; t++) {
            int col = n16 + 16 * t;
            red[wave * 128 + col] = csum[t];
            red[512 + wave * 128 + col] = csq[t];
        }
    }
    __syncthreads();
    if (tid < 128) {
        float s = 0.f, qq = 0.f;
#pragma unroll
        for (int w = 0; w < 4; w++) {
            s += red[w * 128 + tid];
            qq += red[512 + w * 128 + tid];
        }
        unsafeAtomicAdd(&sum_out[tid], s);
        unsafeAtomicAdd(&sq_out[tid], qq);
    }
}

__global__ void bn_fin_k(const float* __restrict__ sum, const float* __restrict__ sq,
        const float* __restrict__ gamma, const float* __restrict__ beta,
        float* __restrict__ scale, float* __restrict__ shift, float invN) {
    int c = threadIdx.x;
    float mean = sum[c] * invN;
    float var = fmaxf(sq[c] * invN - mean * mean, 0.f);
    float sc = gamma[c] * rsqrtf(var + 1e-5f);
    scale[c] = sc;
    shift[c] = beta[c] - mean * sc;
}

__global__ __launch_bounds__(256) void apply_k(float4* __restrict__ z,
        const float4* __restrict__ scale, const float4* __restrict__ shift, int n4) {
    int gid = blockIdx.x * 256 + threadIdx.x;
    if (gid >= n4) return;
    int c4 = gid & 31;
    float4 v = z[gid], s = scale[c4], t = shift[c4];
    v.x = fmaxf(fmaf(v.x, s.x, t.x), 0.f);
    v.y = fmaxf(fmaf(v.y, s.y, t.y), 0.f);
    v.z = fmaxf(fmaf(v.z, s.z, t.z), 0.f);
    v.w = fmaxf(fmaf(v.w, s.w, t.w), 0.f);
    z[gid] = v;
}

extern "C" void kernel_launch(void* const* d_in, const int* in_sizes, int n_in,
                              void* d_out, int out_size, void* d_ws, size_t ws_size,
                              hipStream_t stream) {
    const float* x   = (const float*)d_in[0];
    const int*   ei  = (const int*)d_in[1];
    const int*   ew  = (const int*)d_in[2];
    const float* hc  = (const float*)d_in[3];
    const float* W1  = (const float*)d_in[4];
    const float* b1  = (const float*)d_in[5];
    const float* g1  = (const float*)d_in[6];
    const float* be1 = (const float*)d_in[7];
    const float* W2  = (const float*)d_in[8];
    const float* b2  = (const float*)d_in[9];
    const float* g2  = (const float*)d_in[10];
    const float* be2 = (const float*)d_in[11];

    int N = in_sizes[0] / 128;
    int E = in_sizes[2];
    int K = in_sizes[3];
    int NB = (N + 255) / 256;
    size_t NF = (size_t)N * 128;

    // workspace layout (z1 overlays xb+ecol, which die after gather)
    unsigned short* h_hi = (unsigned short*)d_ws;       // NF ushort
    unsigned short* h_lo = h_hi + NF;                   // NF ushort
    float* z1 = (float*)(h_lo + NF);                    // NF fp32
    unsigned short* xb = (unsigned short*)z1;           // NF ushort  (alias)
    int* ecol = (int*)(xb + NF);                        // E int      (alias)
    int* cnt = (int*)(z1 + NF);                         // N
    int* cur = cnt + N;                                 // N
    int* s1 = cur + N;                                  // N
    int* bscan = s1 + N;                                // 512
    int* bsum = bscan + 512;                            // 512
    unsigned short* w1h = (unsigned short*)(bsum + 512);
    unsigned short* w1l = w1h + 16384;
    unsigned short* w2h = w1l + 16384;
    unsigned short* w2l = w2h + 16384;
    float* aux = (float*)(w2l + 16384);
    float* hwp    = aux;          // 8
    float* sum1   = aux + 8;      // 128
    float* sq1    = aux + 136;    // 128
    float* sum2   = aux + 264;    // 128
    float* sq2    = aux + 392;    // 128
    float* scale1 = aux + 520;    // 128
    float* shift1 = aux + 648;    // 128
    float* scale2 = aux + 776;    // 128
    float* shift2 = aux + 904;    // 128

    hipMemsetAsync(cnt, 0, (size_t)2 * N * sizeof(int), stream);   // cnt + cur
    hipMemsetAsync(sum1, 0, 512 * sizeof(float), stream);          // BN stats

    hop_softmax_k<<<1, 64, 0, stream>>>(hc, hwp, K);
    wsplit_k<<<2, 256, 0, stream>>>(W1, W2, w1h, w1l, w2h, w2l);

    {
        long long n8 = NF / 8;
        xsplit_k<<<(int)((n8 + 255) / 256), 256, 0, stream>>>((const float4*)x, (uint4*)xb, n8);
    }

    int eblocks = (E + 255) / 256;
    count_k<<<eblocks, 256, 0, stream>>>(ei, cnt, E);
    scan1_k<<<NB, 256, 0, stream>>>(cnt, s1, bsum, N);
    scan2_k<<<1, 512, 0, stream>>>(bsum, bscan, NB);
    fill_k<<<eblocks, 256, 0, stream>>>(ei, ei + E, ew, s1, bscan, cur, ecol, E, K);

    {
        long long tot = (long long)N * 64;
        gather_k<<<(int)((tot + 255) / 256), 256, 0, stream>>>((const float2*)x,
            (const unsigned int*)xb, ecol, hwp, s1, bscan, cnt,
            (unsigned int*)h_hi, (unsigned int*)h_lo, N);
    }

    int gblocks = (N + 127) / 128;
    gemm_mfma_k<false><<<gblocks, 256, 0, stream>>>(h_hi, h_lo, nullptr,
        w1h, w1l, b1, nullptr, nullptr, z1, sum1, sq1, N);
    bn_fin_k<<<1, 128, 0, stream>>>(sum1, sq1, g1, be1, scale1, shift1, 1.0f / (float)N);
    gemm_mfma_k<true><<<gblocks, 256, 0, stream>>>(nullptr, nullptr, z1,
        w2h, w2l, b2, scale1, shift1, (float*)d_out, sum2, sq2, N);
    bn_fin_k<<<1, 128, 0, stream>>>(sum2, sq2, g2, be2, scale2, shift2, 1.0f / (float)N);

    {
        int n4 = (int)(NF / 4);
        apply_k<<<(n4 + 255) / 256, 256, 0, stream>>>((float4*)d_out,
            (const float4*)scale2, (const float4*)shift2, n4);
    }
}

// Round 4
// 494.265 us; speedup vs baseline: 6.0830x; 1.1617x over previous
//
#include <hip/hip_runtime.h>
#include <hip/hip_bf16.h>

// ---------------------------------------------------------------------------
// SPN layer (R4): CSR build (ticketed count -> atomic-free fill, 8B payload
// {col,w}) -> bf16 gather with wave-uniform scalar payload reads + unroll-4
// MLP -> split-bf16 MFMA GEMMs (hi/lo residual) -> BN -> relu.
// ---------------------------------------------------------------------------

typedef __attribute__((ext_vector_type(8))) short short8;
typedef __attribute__((ext_vector_type(4))) float f32x4;

__device__ inline unsigned short f2bf(float v) {           // RNE bf16 round
    unsigned int u = __float_as_uint(v);
    unsigned int r = (u + 0x7fffu + ((u >> 16) & 1u)) >> 16;
    return (unsigned short)r;
}
__device__ inline float bf2f(unsigned short u) {
    return __uint_as_float(((unsigned int)u) << 16);
}

__global__ void hop_softmax_k(const float* __restrict__ hc, float* __restrict__ hwp, int K) {
    if (threadIdx.x == 0) {
        float tmp[8];
        float m = -1e30f;
        for (int k = 0; k < K; ++k) m = fmaxf(m, hc[k]);
        float s = 0.f;
        for (int k = 0; k < K; ++k) { float e = __expf(hc[k] - m); tmp[k] = e; s += e; }
        float inv = 1.f / s;
        for (int k = 0; k < 8; ++k) hwp[k] = 0.f;
        for (int k = 0; k < K; ++k) hwp[k + 1] = tmp[k] * inv;  // hwp[d], d=1..K
    }
}

// x fp32 -> bf16 (gather payload)
__global__ __launch_bounds__(256) void xsplit_k(const float4* __restrict__ x4,
        uint4* __restrict__ xb, long long n8) {
    long long g = (long long)blockIdx.x * 256 + threadIdx.x;
    if (g >= n8) return;
    float4 a = x4[g * 2], b = x4[g * 2 + 1];
    union { unsigned short us[8]; uint4 v; } o;
    o.us[0] = f2bf(a.x); o.us[1] = f2bf(a.y); o.us[2] = f2bf(a.z); o.us[3] = f2bf(a.w);
    o.us[4] = f2bf(b.x); o.us[5] = f2bf(b.y); o.us[6] = f2bf(b.z); o.us[7] = f2bf(b.w);
    xb[g] = o.v;
}

// W [k][n] fp32 -> transposed split Wt_hi/Wt_lo [n][k] bf16
__global__ __launch_bounds__(256) void wsplit_k(const float* __restrict__ W1,
        const float* __restrict__ W2, unsigned short* __restrict__ w1h,
        unsigned short* __restrict__ w1l, unsigned short* __restrict__ w2h,
        unsigned short* __restrict__ w2l) {
    const float* W = blockIdx.x ? W2 : W1;
    unsigned short* th = blockIdx.x ? w2h : w1h;
    unsigned short* tl = blockIdx.x ? w2l : w1l;
    for (int i = threadIdx.x; i < 16384; i += 256) {
        int k = i >> 7, n = i & 127;
        float v = W[k * 128 + n];
        unsigned short hi = f2bf(v);
        th[n * 128 + k] = hi;
        tl[n * 128 + k] = f2bf(v - bf2f(hi));
    }
}

// --- CSR build ---------------------------------------------------------------
// ticketed count: seq[e] = within-row arrival order (makes fill atomic-free)
__global__ __launch_bounds__(256) void count_k(const int* __restrict__ rows,
        int* __restrict__ cnt, int* __restrict__ seq, int E) {
    int e = blockIdx.x * 256 + threadIdx.x;
    if (e < E) seq[e] = atomicAdd(&cnt[rows[e]], 1);
}

__global__ __launch_bounds__(256) void scan1_k(const int* __restrict__ cnt,
        int* __restrict__ s1, int* __restrict__ bsum, int N) {
    __shared__ int lds[256];
    int t = threadIdx.x;
    int i = blockIdx.x * 256 + t;
    int v = (i < N) ? cnt[i] : 0;
    lds[t] = v;
    __syncthreads();
#pragma unroll
    for (int off = 1; off < 256; off <<= 1) {
        int a = lds[t];
        int b = (t >= off) ? lds[t - off] : 0;
        __syncthreads();
        lds[t] = a + b;
        __syncthreads();
    }
    if (i < N) s1[i] = lds[t] - v;
    if (t == 255) bsum[blockIdx.x] = lds[255];
}

__global__ __launch_bounds__(512) void scan2_k(const int* __restrict__ bsum,
        int* __restrict__ bscan, int NB) {
    __shared__ int lds[512];
    int t = threadIdx.x;
    int v = (t < NB) ? bsum[t] : 0;
    lds[t] = v;
    __syncthreads();
#pragma unroll
    for (int off = 1; off < 512; off <<= 1) {
        int a = lds[t];
        int b = (t >= off) ? lds[t - off] : 0;
        __syncthreads();
        lds[t] = a + b;
        __syncthreads();
    }
    if (t < NB) bscan[t] = lds[t] - v;
}

// rowptr[i] = global exclusive prefix (one random read in fill instead of two)
__global__ __launch_bounds__(256) void rowfin_k(const int* __restrict__ s1,
        const int* __restrict__ bscan, int* __restrict__ rowptr, int N) {
    int i = blockIdx.x * 256 + threadIdx.x;
    if (i < N) rowptr[i] = s1[i] + bscan[i >> 8];
}

// atomic-free fill: payload {col, w_as_float_bits}
__global__ __launch_bounds__(256) void fill_k(const int* __restrict__ rows,
        const int* __restrict__ cols, const int* __restrict__ ew,
        const int* __restrict__ seq, const int* __restrict__ rowptr,
        const float* __restrict__ hwp, int2* __restrict__ epay, int E, int K) {
    int e = blockIdx.x * 256 + threadIdx.x;
    if (e >= E) return;
    int d = ew[e];
    if (d < 1 || d > K) d = 0;                 // hwp[0] = 0 -> weight 0
    float w = hwp[d];
    int pos = rowptr[rows[e]] + seq[e];
    epay[pos] = make_int2(cols[e], __float_as_int(w));
}

// one wave per row: h = x[row] + sum_j w_j * xb[col_j]; write h as bf16 hi/lo.
// payload reads are wave-uniform (scalar path); 4 xb row-loads kept in flight.
__global__ __launch_bounds__(256) void gather_k(const float2* __restrict__ x2,
        const unsigned int* __restrict__ xb,  // bf16 x as uint (2 elems/lane)
        const int2* __restrict__ epay, const int* __restrict__ rowptr,
        const int* __restrict__ cnt, unsigned int* __restrict__ hhi2,
        unsigned int* __restrict__ hlo2, int N) {
    int wid = (blockIdx.x * 256 + threadIdx.x) >> 6;
    if (wid >= N) return;
    int lane = threadIdx.x & 63;
    int start = __builtin_amdgcn_readfirstlane(rowptr[wid]);
    int deg = __builtin_amdgcn_readfirstlane(cnt[wid]);
    const int2* ep = epay + start;
    const unsigned int* xbl = xb + lane;
    float2 acc = x2[(size_t)wid * 64 + lane];          // GIN self term (eps=0)
    int j = 0;
    for (; j + 4 <= deg; j += 4) {
        int2 p0 = ep[j + 0];
        int2 p1 = ep[j + 1];
        int2 p2 = ep[j + 2];
        int2 p3 = ep[j + 3];
        unsigned int u0 = xbl[(size_t)p0.x * 64];
        unsigned int u1 = xbl[(size_t)p1.x * 64];
        unsigned int u2 = xbl[(size_t)p2.x * 64];
        unsigned int u3 = xbl[(size_t)p3.x * 64];
        float w0 = __int_as_float(p0.y), w1 = __int_as_float(p1.y);
        float w2 = __int_as_float(p2.y), w3 = __int_as_float(p3.y);
        acc.x = fmaf(w0, bf2f((unsigned short)(u0 & 0xFFFF)), acc.x);
        acc.y = fmaf(w0, bf2f((unsigned short)(u0 >> 16)), acc.y);
        acc.x = fmaf(w1, bf2f((unsigned short)(u1 & 0xFFFF)), acc.x);
        acc.y = fmaf(w1, bf2f((unsigned short)(u1 >> 16)), acc.y);
        acc.x = fmaf(w2, bf2f((unsigned short)(u2 & 0xFFFF)), acc.x);
        acc.y = fmaf(w2, bf2f((unsigned short)(u2 >> 16)), acc.y);
        acc.x = fmaf(w3, bf2f((unsigned short)(u3 & 0xFFFF)), acc.x);
        acc.y = fmaf(w3, bf2f((unsigned short)(u3 >> 16)), acc.y);
    }
    for (; j < deg; ++j) {
        int2 p = ep[j];
        unsigned int u = xbl[(size_t)p.x * 64];
        float w = __int_as_float(p.y);
        acc.x = fmaf(w, bf2f((unsigned short)(u & 0xFFFF)), acc.x);
        acc.y = fmaf(w, bf2f((unsigned short)(u >> 16)), acc.y);
    }
    unsigned short hx = f2bf(acc.x), hy = f2bf(acc.y);
    hhi2[(size_t)wid * 64 + lane] = (unsigned int)hx | ((unsigned int)hy << 16);
    unsigned short lx = f2bf(acc.x - bf2f(hx)), ly = f2bf(acc.y - bf2f(hy));
    hlo2[(size_t)wid * 64 + lane] = (unsigned int)lx | ((unsigned int)ly << 16);
}

// --- split-bf16 MFMA GEMM + bias + column stats ------------------------------
template<bool AFFINE>
__global__ __launch_bounds__(256) void gemm_mfma_k(
        const unsigned short* __restrict__ Ahi, const unsigned short* __restrict__ Alo,
        const float* __restrict__ Az,
        const unsigned short* __restrict__ Bhg, const unsigned short* __restrict__ Blg,
        const float* __restrict__ bias,
        const float* __restrict__ scale_in, const float* __restrict__ shift_in,
        float* __restrict__ zout, float* __restrict__ sum_out, float* __restrict__ sq_out,
        int N) {
    __shared__ unsigned short Bh[128 * 136];
    __shared__ unsigned short Bl[128 * 136];
    int tid = threadIdx.x;
    for (int i = tid; i < 4096; i += 256) {
        int half = i >> 11;
        int j = i & 2047;
        int n = j >> 4, c = j & 15;
        const uint4* src = (const uint4*)((half ? Blg : Bhg) + n * 128 + c * 8);
        uint4* dst = (uint4*)((half ? Bl : Bh) + n * 136 + c * 8);
        *dst = *src;
    }
    __syncthreads();

    int wave = tid >> 6, lane = tid & 63;
    int n16 = lane & 15, q = lane >> 4;
    int rowbase = blockIdx.x * 128 + wave * 32;

    f32x4 acc[2][8];
#pragma unroll
    for (int mt = 0; mt < 2; mt++)
#pragma unroll
        for (int t = 0; t < 8; t++) acc[mt][t] = (f32x4){0.f, 0.f, 0.f, 0.f};

    int ldsb = n16 * 136 + q * 8;

#pragma unroll
    for (int k0 = 0; k0 < 128; k0 += 32) {
        short8 ahi[2], alo[2];
#pragma unroll
        for (int mt = 0; mt < 2; mt++) {
            int ar = rowbase + mt * 16 + n16;
            ar = min(ar, N - 1);
            size_t off = (size_t)ar * 128 + k0 + q * 8;
            if (!AFFINE) {
                ahi[mt] = *(const short8*)(Ahi + off);
                alo[mt] = *(const short8*)(Alo + off);
            } else {
                const float4* zp = (const float4*)(Az + off);
                float4 z0 = zp[0], z1 = zp[1];
                const float4* sp = (const float4*)(scale_in + k0 + q * 8);
                const float4* tp = (const float4*)(shift_in + k0 + q * 8);
                float4 s0 = sp[0], s1 = sp[1], t0 = tp[0], t1 = tp[1];
                float v[8];
                v[0] = fmaxf(fmaf(z0.x, s0.x, t0.x), 0.f);
                v[1] = fmaxf(fmaf(z0.y, s0.y, t0.y), 0.f);
                v[2] = fmaxf(fmaf(z0.z, s0.z, t0.z), 0.f);
                v[3] = fmaxf(fmaf(z0.w, s0.w, t0.w), 0.f);
                v[4] = fmaxf(fmaf(z1.x, s1.x, t1.x), 0.f);
                v[5] = fmaxf(fmaf(z1.y, s1.y, t1.y), 0.f);
                v[6] = fmaxf(fmaf(z1.z, s1.z, t1.z), 0.f);
                v[7] = fmaxf(fmaf(z1.w, s1.w, t1.w), 0.f);
#pragma unroll
                for (int e = 0; e < 8; e++) {
                    unsigned short hb = f2bf(v[e]);
                    ahi[mt][e] = (short)hb;
                    alo[mt][e] = (short)f2bf(v[e] - bf2f(hb));
                }
            }
        }
#pragma unroll
        for (int t = 0; t < 8; t++) {
            short8 bhi = *(const short8*)&Bh[t * 16 * 136 + ldsb + k0];
            short8 blo = *(const short8*)&Bl[t * 16 * 136 + ldsb + k0];
#pragma unroll
            for (int mt = 0; mt < 2; mt++) {
                acc[mt][t] = __builtin_amdgcn_mfma_f32_16x16x32_bf16(ahi[mt], bhi, acc[mt][t], 0, 0, 0);
                acc[mt][t] = __builtin_amdgcn_mfma_f32_16x16x32_bf16(alo[mt], bhi, acc[mt][t], 0, 0, 0);
                acc[mt][t] = __builtin_amdgcn_mfma_f32_16x16x32_bf16(ahi[mt], blo, acc[mt][t], 0, 0, 0);
            }
        }
    }

    float csum[8], csq[8];
#pragma unroll
    for (int t = 0; t < 8; t++) { csum[t] = 0.f; csq[t] = 0.f; }
#pragma unroll
    for (int t = 0; t < 8; t++) {
        int col = n16 + 16 * t;
        float bv = bias[col];
#pragma unroll
        for (int mt = 0; mt < 2; mt++) {
#pragma unroll
            for (int r = 0; r < 4; r++) {
                int row = rowbase + mt * 16 + q * 4 + r;
                if (row < N) {
                    float v = acc[mt][t][r] + bv;
                    zout[(size_t)row * 128 + col] = v;
                    csum[t] += v;
                    csq[t] += v * v;
                }
            }
        }
    }
#pragma unroll
    for (int t = 0; t < 8; t++) {
        csum[t] += __shfl_xor(csum[t], 16);
        csum[t] += __shfl_xor(csum[t], 32);
        csq[t] += __shfl_xor(csq[t], 16);
        csq[t] += __shfl_xor(csq[t], 32);
    }
    __syncthreads();
    float* red = (float*)Bh;
    if (q == 0) {
#pragma unroll
        for (int t = 0; t < 8; t++) {
            int col = n16 + 16 * t;
            red[wave * 128 + col] = csum[t];
            red[512 + wave * 128 + col] = csq[t];
        }
    }
    __syncthreads();
    if (tid < 128) {
        float s = 0.f, qq = 0.f;
#pragma unroll
        for (int w = 0; w < 4; w++) {
            s += red[w * 128 + tid];
            qq += red[512 + w * 128 + tid];
        }
        unsafeAtomicAdd(&sum_out[tid], s);
        unsafeAtomicAdd(&sq_out[tid], qq);
    }
}

__global__ void bn_fin_k(const float* __restrict__ sum, const float* __restrict__ sq,
        const float* __restrict__ gamma, const float* __restrict__ beta,
        float* __restrict__ scale, float* __restrict__ shift, float invN) {
    int c = threadIdx.x;
    float mean = sum[c] * invN;
    float var = fmaxf(sq[c] * invN - mean * mean, 0.f);
    float sc = gamma[c] * rsqrtf(var + 1e-5f);
    scale[c] = sc;
    shift[c] = beta[c] - mean * sc;
}

__global__ __launch_bounds__(256) void apply_k(float4* __restrict__ z,
        const float4* __restrict__ scale, const float4* __restrict__ shift, int n4) {
    int gid = blockIdx.x * 256 + threadIdx.x;
    if (gid >= n4) return;
    int c4 = gid & 31;
    float4 v = z[gid], s = scale[c4], t = shift[c4];
    v.x = fmaxf(fmaf(v.x, s.x, t.x), 0.f);
    v.y = fmaxf(fmaf(v.y, s.y, t.y), 0.f);
    v.z = fmaxf(fmaf(v.z, s.z, t.z), 0.f);
    v.w = fmaxf(fmaf(v.w, s.w, t.w), 0.f);
    z[gid] = v;
}

extern "C" void kernel_launch(void* const* d_in, const int* in_sizes, int n_in,
                              void* d_out, int out_size, void* d_ws, size_t ws_size,
                              hipStream_t stream) {
    const float* x   = (const float*)d_in[0];
    const int*   ei  = (const int*)d_in[1];
    const int*   ew  = (const int*)d_in[2];
    const float* hc  = (const float*)d_in[3];
    const float* W1  = (const float*)d_in[4];
    const float* b1  = (const float*)d_in[5];
    const float* g1  = (const float*)d_in[6];
    const float* be1 = (const float*)d_in[7];
    const float* W2  = (const float*)d_in[8];
    const float* b2  = (const float*)d_in[9];
    const float* g2  = (const float*)d_in[10];
    const float* be2 = (const float*)d_in[11];

    int N = in_sizes[0] / 128;
    int E = in_sizes[2];
    int K = in_sizes[3];
    int NB = (N + 255) / 256;
    size_t NF = (size_t)N * 128;

    // workspace layout (z1 overlays xb+epay, which die after gather)
    unsigned short* h_hi = (unsigned short*)d_ws;       // NF ushort
    unsigned short* h_lo = h_hi + NF;                   // NF ushort
    float* z1 = (float*)(h_lo + NF);                    // NF fp32
    unsigned short* xb = (unsigned short*)z1;           // NF ushort  (alias)
    int2* epay = (int2*)(xb + NF);                      // E int2     (alias)
    int* cnt = (int*)(z1 + NF);                         // N
    int* s1 = cnt + N;                                  // N
    int* rowptr = s1 + N;                               // N
    int* bscan = rowptr + N;                            // 512
    int* bsum = bscan + 512;                            // 512
    int* seq = bsum + 512;                              // E
    unsigned short* w1h = (unsigned short*)(seq + E);
    unsigned short* w1l = w1h + 16384;
    unsigned short* w2h = w1l + 16384;
    unsigned short* w2l = w2h + 16384;
    float* aux = (float*)(w2l + 16384);
    float* hwp    = aux;          // 8
    float* sum1   = aux + 8;      // 128
    float* sq1    = aux + 136;    // 128
    float* sum2   = aux + 264;    // 128
    float* sq2    = aux + 392;    // 128
    float* scale1 = aux + 520;    // 128
    float* shift1 = aux + 648;    // 128
    float* scale2 = aux + 776;    // 128
    float* shift2 = aux + 904;    // 128

    hipMemsetAsync(cnt, 0, (size_t)N * sizeof(int), stream);
    hipMemsetAsync(sum1, 0, 512 * sizeof(float), stream);          // BN stats

    hop_softmax_k<<<1, 64, 0, stream>>>(hc, hwp, K);
    wsplit_k<<<2, 256, 0, stream>>>(W1, W2, w1h, w1l, w2h, w2l);

    {
        long long n8 = NF / 8;
        xsplit_k<<<(int)((n8 + 255) / 256), 256, 0, stream>>>((const float4*)x, (uint4*)xb, n8);
    }

    int eblocks = (E + 255) / 256;
    count_k<<<eblocks, 256, 0, stream>>>(ei, cnt, seq, E);
    scan1_k<<<NB, 256, 0, stream>>>(cnt, s1, bsum, N);
    scan2_k<<<1, 512, 0, stream>>>(bsum, bscan, NB);
    rowfin_k<<<(N + 255) / 256, 256, 0, stream>>>(s1, bscan, rowptr, N);
    fill_k<<<eblocks, 256, 0, stream>>>(ei, ei + E, ew, seq, rowptr, hwp, epay, E, K);

    {
        long long tot = (long long)N * 64;
        gather_k<<<(int)((tot + 255) / 256), 256, 0, stream>>>((const float2*)x,
            (const unsigned int*)xb, epay, rowptr, cnt,
            (unsigned int*)h_hi, (unsigned int*)h_lo, N);
    }

    int gblocks = (N + 127) / 128;
    gemm_mfma_k<false><<<gblocks, 256, 0, stream>>>(h_hi, h_lo, nullptr,
        w1h, w1l, b1, nullptr, nullptr, z1, sum1, sq1, N);
    bn_fin_k<<<1, 128, 0, stream>>>(sum1, sq1, g1, be1, scale1, shift1, 1.0f / (float)N);
    gemm_mfma_k<true><<<gblocks, 256, 0, stream>>>(nullptr, nullptr, z1,
        w2h, w2l, b2, scale1, shift1, (float*)d_out, sum2, sq2, N);
    bn_fin_k<<<1, 128, 0, stream>>>(sum2, sq2, g2, be2, scale2, shift2, 1.0f / (float)N);

    {
        int n4 = (int)(NF / 4);
        apply_k<<<(n4 + 255) / 256, 256, 0, stream>>>((float4*)d_out,
            (const float4*)scale2, (const float4*)shift2, n4);
    }
}

// Round 5
// 460.162 us; speedup vs baseline: 6.5338x; 1.0741x over previous
//
#include <hip/hip_runtime.h>
#include <hip/hip_bf16.h>

// ---------------------------------------------------------------------------
// SPN layer (R5): one prep kernel (softmax/W-split/x->bf16/zeroing) ->
// ticketed count (x4 MLP) -> scan -> fill (x4) -> 2-edges-per-wave bf16
// gather -> bf16 MFMA GEMM1 (W split hi/lo) -> GEMM2 (BN1 fused in prologue)
// -> apply (BN2 fused). 9 dispatches, bf16 intermediates everywhere.
// ---------------------------------------------------------------------------

typedef __attribute__((ext_vector_type(8))) short short8;
typedef __attribute__((ext_vector_type(4))) float f32x4;

__device__ inline unsigned short f2bf(float v) {           // RNE bf16 round
    unsigned int u = __float_as_uint(v);
    unsigned int r = (u + 0x7fffu + ((u >> 16) & 1u)) >> 16;
    return (unsigned short)r;
}
__device__ inline float bf2f(unsigned int u) {
    return __uint_as_float(u << 16);
}

// --- prep: [0]=softmax+zero stats, [1..2]=W split, [3..3+NBC)=cnt zero,
//           [3+NBC..)=x->bf16 -----------------------------------------------
__global__ __launch_bounds__(256) void prep_k(const float* __restrict__ hc,
        float* __restrict__ hwp, float* __restrict__ sums,
        const float* __restrict__ W1, const float* __restrict__ W2,
        unsigned short* __restrict__ w1h, unsigned short* __restrict__ w1l,
        unsigned short* __restrict__ w2h, unsigned short* __restrict__ w2l,
        int* __restrict__ cnt, const float4* __restrict__ x4,
        uint4* __restrict__ xb, int N, int K, int NBC, long long n8) {
    int b = blockIdx.x, tid = threadIdx.x;
    if (b == 0) {
        sums[tid] = 0.f; sums[tid + 256] = 0.f;          // sum1|sq1|sum2|sq2
        if (tid == 0) {
            float tmp[8];
            float m = -1e30f;
            for (int k = 0; k < K; ++k) m = fmaxf(m, hc[k]);
            float s = 0.f;
            for (int k = 0; k < K; ++k) { float e = __expf(hc[k] - m); tmp[k] = e; s += e; }
            float inv = 1.f / s;
            for (int k = 0; k < 8; ++k) hwp[k] = 0.f;
            for (int k = 0; k < K; ++k) hwp[k + 1] = tmp[k] * inv;
        }
        return;
    }
    if (b <= 2) {
        const float* W = (b == 2) ? W2 : W1;
        unsigned short* th = (b == 2) ? w2h : w1h;
        unsigned short* tl = (b == 2) ? w2l : w1l;
        for (int i = tid; i < 16384; i += 256) {
            int k = i >> 7, n = i & 127;
            float v = W[k * 128 + n];
            unsigned short hi = f2bf(v);
            th[n * 128 + k] = hi;
            tl[n * 128 + k] = f2bf(v - bf2f(hi));
        }
        return;
    }
    if (b < 3 + NBC) {
        int i = (b - 3) * 256 + tid;
        if (i < N) cnt[i] = 0;
        return;
    }
    long long g = (long long)(b - 3 - NBC) * 256 + tid;
    if (g >= n8) return;
    float4 a = x4[g * 2], c = x4[g * 2 + 1];
    union { unsigned short us[8]; uint4 v; } o;
    o.us[0] = f2bf(a.x); o.us[1] = f2bf(a.y); o.us[2] = f2bf(a.z); o.us[3] = f2bf(a.w);
    o.us[4] = f2bf(c.x); o.us[5] = f2bf(c.y); o.us[6] = f2bf(c.z); o.us[7] = f2bf(c.w);
    xb[g] = o.v;
}

// --- CSR build: ticketed count, 4 edges/thread ------------------------------
__global__ __launch_bounds__(256) void count_k(const int* __restrict__ rows,
        int* __restrict__ cnt, int* __restrict__ seq, int E) {
    int g = blockIdx.x * 256 + threadIdx.x;
    int e0 = g * 4;
    if (e0 + 4 <= E) {
        int4 r = ((const int4*)rows)[g];
        int4 s;
        s.x = atomicAdd(&cnt[r.x], 1);
        s.y = atomicAdd(&cnt[r.y], 1);
        s.z = atomicAdd(&cnt[r.z], 1);
        s.w = atomicAdd(&cnt[r.w], 1);
        ((int4*)seq)[g] = s;
    } else {
        for (int e = e0; e < E; ++e) seq[e] = atomicAdd(&cnt[rows[e]], 1);
    }
}

__global__ __launch_bounds__(256) void scan1_k(const int* __restrict__ cnt,
        int* __restrict__ s1, int* __restrict__ bsum, int N) {
    __shared__ int lds[256];
    int t = threadIdx.x;
    int i = blockIdx.x * 256 + t;
    int v = (i < N) ? cnt[i] : 0;
    lds[t] = v;
    __syncthreads();
#pragma unroll
    for (int off = 1; off < 256; off <<= 1) {
        int a = lds[t];
        int b = (t >= off) ? lds[t - off] : 0;
        __syncthreads();
        lds[t] = a + b;
        __syncthreads();
    }
    if (i < N) s1[i] = lds[t] - v;
    if (t == 255) bsum[blockIdx.x] = lds[255];
}

__global__ __launch_bounds__(512) void scan2_k(const int* __restrict__ bsum,
        int* __restrict__ bscan, int NB) {
    __shared__ int lds[512];
    int t = threadIdx.x;
    int v = (t < NB) ? bsum[t] : 0;
    lds[t] = v;
    __syncthreads();
#pragma unroll
    for (int off = 1; off < 512; off <<= 1) {
        int a = lds[t];
        int b = (t >= off) ? lds[t - off] : 0;
        __syncthreads();
        lds[t] = a + b;
        __syncthreads();
    }
    if (t < NB) bscan[t] = lds[t] - v;
}

// atomic-free fill, 4 edges/thread; payload {col, w_bits}
__global__ __launch_bounds__(256) void fill_k(const int* __restrict__ rows,
        const int* __restrict__ cols, const int* __restrict__ ew,
        const int* __restrict__ seq, const int* __restrict__ s1,
        const int* __restrict__ bscan, const float* __restrict__ hwp,
        int2* __restrict__ epay, int E, int K) {
    int g = blockIdx.x * 256 + threadIdx.x;
    int e0 = g * 4;
    if (e0 + 4 <= E) {
        int4 r = ((const int4*)rows)[g];
        int4 c = ((const int4*)cols)[g];
        int4 d = ((const int4*)ew)[g];
        int4 s = ((const int4*)seq)[g];
        int dd;
        dd = (d.x < 1 || d.x > K) ? 0 : d.x;
        epay[s1[r.x] + bscan[r.x >> 8] + s.x] = make_int2(c.x, __float_as_int(hwp[dd]));
        dd = (d.y < 1 || d.y > K) ? 0 : d.y;
        epay[s1[r.y] + bscan[r.y >> 8] + s.y] = make_int2(c.y, __float_as_int(hwp[dd]));
        dd = (d.z < 1 || d.z > K) ? 0 : d.z;
        epay[s1[r.z] + bscan[r.z >> 8] + s.z] = make_int2(c.z, __float_as_int(hwp[dd]));
        dd = (d.w < 1 || d.w > K) ? 0 : d.w;
        epay[s1[r.w] + bscan[r.w >> 8] + s.w] = make_int2(c.w, __float_as_int(hwp[dd]));
    } else {
        for (int e = e0; e < E; ++e) {
            int d = ew[e];
            if (d < 1 || d > K) d = 0;
            int r = rows[e];
            epay[s1[r] + bscan[r >> 8] + seq[e]] = make_int2(cols[e], __float_as_int(hwp[d]));
        }
    }
}

// one wave per row, 2 edges per step (32 lanes x 8B each); h bf16 out
__global__ __launch_bounds__(256) void gather_k(
        const unsigned short* __restrict__ xb, const int2* __restrict__ epay,
        const int* __restrict__ s1, const int* __restrict__ bscan,
        const int* __restrict__ cnt, unsigned short* __restrict__ h, int N) {
    int wid = (blockIdx.x * 256 + threadIdx.x) >> 6;
    if (wid >= N) return;
    int lane = threadIdx.x & 63;
    int half = lane >> 5, li = lane & 31;
    int start = __builtin_amdgcn_readfirstlane(s1[wid] + bscan[wid >> 8]);
    int deg = __builtin_amdgcn_readfirstlane(cnt[wid]);
    const int2* ep = epay + start;
    float a0 = 0.f, a1 = 0.f, a2 = 0.f, a3 = 0.f;
    if (half == 0) {                                    // GIN self term (eps=0)
        uint2 u = *(const uint2*)(xb + (size_t)wid * 128 + li * 4);
        a0 = bf2f(u.x & 0xFFFF); a1 = bf2f(u.x >> 16);
        a2 = bf2f(u.y & 0xFFFF); a3 = bf2f(u.y >> 16);
    }
    int j = 0;
    for (; j + 8 <= deg; j += 8) {
        int2 p0 = ep[j + 0 + half];
        int2 p1 = ep[j + 2 + half];
        int2 p2 = ep[j + 4 + half];
        int2 p3 = ep[j + 6 + half];
        uint2 u0 = *(const uint2*)(xb + (size_t)p0.x * 128 + li * 4);
        uint2 u1 = *(const uint2*)(xb + (size_t)p1.x * 128 + li * 4);
        uint2 u2 = *(const uint2*)(xb + (size_t)p2.x * 128 + li * 4);
        uint2 u3 = *(const uint2*)(xb + (size_t)p3.x * 128 + li * 4);
        float w0 = __int_as_float(p0.y), w1 = __int_as_float(p1.y);
        float w2 = __int_as_float(p2.y), w3 = __int_as_float(p3.y);
        a0 = fmaf(w0, bf2f(u0.x & 0xFFFF), a0); a1 = fmaf(w0, bf2f(u0.x >> 16), a1);
        a2 = fmaf(w0, bf2f(u0.y & 0xFFFF), a2); a3 = fmaf(w0, bf2f(u0.y >> 16), a3);
        a0 = fmaf(w1, bf2f(u1.x & 0xFFFF), a0); a1 = fmaf(w1, bf2f(u1.x >> 16), a1);
        a2 = fmaf(w1, bf2f(u1.y & 0xFFFF), a2); a3 = fmaf(w1, bf2f(u1.y >> 16), a3);
        a0 = fmaf(w2, bf2f(u2.x & 0xFFFF), a0); a1 = fmaf(w2, bf2f(u2.x >> 16), a1);
        a2 = fmaf(w2, bf2f(u2.y & 0xFFFF), a2); a3 = fmaf(w2, bf2f(u2.y >> 16), a3);
        a0 = fmaf(w3, bf2f(u3.x & 0xFFFF), a0); a1 = fmaf(w3, bf2f(u3.x >> 16), a1);
        a2 = fmaf(w3, bf2f(u3.y & 0xFFFF), a2); a3 = fmaf(w3, bf2f(u3.y >> 16), a3);
    }
    for (; j + 2 <= deg; j += 2) {
        int2 p = ep[j + half];
        float w = __int_as_float(p.y);
        uint2 u = *(const uint2*)(xb + (size_t)p.x * 128 + li * 4);
        a0 = fmaf(w, bf2f(u.x & 0xFFFF), a0); a1 = fmaf(w, bf2f(u.x >> 16), a1);
        a2 = fmaf(w, bf2f(u.y & 0xFFFF), a2); a3 = fmaf(w, bf2f(u.y >> 16), a3);
    }
    if (j < deg) {                                      // odd tail: half 1 idle
        int2 p = ep[j];
        float w = half ? 0.f : __int_as_float(p.y);
        uint2 u = *(const uint2*)(xb + (size_t)p.x * 128 + li * 4);
        a0 = fmaf(w, bf2f(u.x & 0xFFFF), a0); a1 = fmaf(w, bf2f(u.x >> 16), a1);
        a2 = fmaf(w, bf2f(u.y & 0xFFFF), a2); a3 = fmaf(w, bf2f(u.y >> 16), a3);
    }
    a0 += __shfl_xor(a0, 32); a1 += __shfl_xor(a1, 32);
    a2 += __shfl_xor(a2, 32); a3 += __shfl_xor(a3, 32);
    if (half == 0) {
        uint2 o;
        o.x = (unsigned int)f2bf(a0) | ((unsigned int)f2bf(a1) << 16);
        o.y = (unsigned int)f2bf(a2) | ((unsigned int)f2bf(a3) << 16);
        *(uint2*)(h + (size_t)wid * 128 + li * 4) = o;
    }
}

// --- bf16 MFMA GEMM: A single-bf16, B split hi/lo (2-term) ------------------
// AFFINE: A = bf16(relu(scale*z + shift)), scale/shift computed per block
// from global sums (BN fold). Output z stored bf16; column stats to sums.
template<bool AFFINE>
__global__ __launch_bounds__(256) void gemm_mfma_k(
        const unsigned short* __restrict__ Ain,     // h bf16  (or z1 bf16)
        const unsigned short* __restrict__ Bhg, const unsigned short* __restrict__ Blg,
        const float* __restrict__ bias,
        const float* __restrict__ sum_in, const float* __restrict__ sq_in,
        const float* __restrict__ gamma, const float* __restrict__ beta,
        unsigned short* __restrict__ zout,
        float* __restrict__ sum_out, float* __restrict__ sq_out,
        int N, float invN) {
    __shared__ unsigned short Bh[128 * 136];
    __shared__ unsigned short Bl[128 * 136];
    __shared__ float sc_s[128], sh_s[128];
    int tid = threadIdx.x;
    if (AFFINE && tid < 128) {
        float mean = sum_in[tid] * invN;
        float var = fmaxf(sq_in[tid] * invN - mean * mean, 0.f);
        float s = gamma[tid] * rsqrtf(var + 1e-5f);
        sc_s[tid] = s;
        sh_s[tid] = beta[tid] - mean * s;
    }
    for (int i = tid; i < 4096; i += 256) {
        int halfb = i >> 11;
        int j = i & 2047;
        int n = j >> 4, c = j & 15;
        const uint4* src = (const uint4*)((halfb ? Blg : Bhg) + n * 128 + c * 8);
        uint4* dst = (uint4*)((halfb ? Bl : Bh) + n * 136 + c * 8);
        *dst = *src;
    }
    __syncthreads();

    int wave = tid >> 6, lane = tid & 63;
    int n16 = lane & 15, q = lane >> 4;
    int rowbase = blockIdx.x * 128 + wave * 32;

    f32x4 acc[2][8];
#pragma unroll
    for (int mt = 0; mt < 2; mt++)
#pragma unroll
        for (int t = 0; t < 8; t++) acc[mt][t] = (f32x4){0.f, 0.f, 0.f, 0.f};

    int ldsb = n16 * 136 + q * 8;

#pragma unroll
    for (int k0 = 0; k0 < 128; k0 += 32) {
        short8 afr[2];
        float4 s0, s1v, t0, t1;
        if (AFFINE) {
            s0 = *(const float4*)&sc_s[k0 + q * 8];
            s1v = *(const float4*)&sc_s[k0 + q * 8 + 4];
            t0 = *(const float4*)&sh_s[k0 + q * 8];
            t1 = *(const float4*)&sh_s[k0 + q * 8 + 4];
        }
#pragma unroll
        for (int mt = 0; mt < 2; mt++) {
            int ar = rowbase + mt * 16 + n16;
            ar = min(ar, N - 1);
            size_t off = (size_t)ar * 128 + k0 + q * 8;
            short8 raw = *(const short8*)(Ain + off);
            if (!AFFINE) {
                afr[mt] = raw;
            } else {
                float v[8];
                v[0] = fmaxf(fmaf(bf2f((unsigned short)raw[0]), s0.x, t0.x), 0.f);
                v[1] = fmaxf(fmaf(bf2f((unsigned short)raw[1]), s0.y, t0.y), 0.f);
                v[2] = fmaxf(fmaf(bf2f((unsigned short)raw[2]), s0.z, t0.z), 0.f);
                v[3] = fmaxf(fmaf(bf2f((unsigned short)raw[3]), s0.w, t0.w), 0.f);
                v[4] = fmaxf(fmaf(bf2f((unsigned short)raw[4]), s1v.x, t1.x), 0.f);
                v[5] = fmaxf(fmaf(bf2f((unsigned short)raw[5]), s1v.y, t1.y), 0.f);
                v[6] = fmaxf(fmaf(bf2f((unsigned short)raw[6]), s1v.z, t1.z), 0.f);
                v[7] = fmaxf(fmaf(bf2f((unsigned short)raw[7]), s1v.w, t1.w), 0.f);
#pragma unroll
                for (int e = 0; e < 8; e++) afr[mt][e] = (short)f2bf(v[e]);
            }
        }
#pragma unroll
        for (int t = 0; t < 8; t++) {
            short8 bhi = *(const short8*)&Bh[t * 16 * 136 + ldsb + k0];
            short8 blo = *(const short8*)&Bl[t * 16 * 136 + ldsb + k0];
#pragma unroll
            for (int mt = 0; mt < 2; mt++) {
                acc[mt][t] = __builtin_amdgcn_mfma_f32_16x16x32_bf16(afr[mt], bhi, acc[mt][t], 0, 0, 0);
                acc[mt][t] = __builtin_amdgcn_mfma_f32_16x16x32_bf16(afr[mt], blo, acc[mt][t], 0, 0, 0);
            }
        }
    }

    float csum[8], csq[8];
#pragma unroll
    for (int t = 0; t < 8; t++) { csum[t] = 0.f; csq[t] = 0.f; }
#pragma unroll
    for (int t = 0; t < 8; t++) {
        int col = n16 + 16 * t;
        float bv = bias[col];
#pragma unroll
        for (int mt = 0; mt < 2; mt++) {
#pragma unroll
            for (int r = 0; r < 4; r++) {
                int row = rowbase + mt * 16 + q * 4 + r;
                if (row < N) {
                    float v = acc[mt][t][r] + bv;
                    zout[(size_t)row * 128 + col] = f2bf(v);
                    csum[t] += v;
                    csq[t] += v * v;
                }
            }
        }
    }
#pragma unroll
    for (int t = 0; t < 8; t++) {
        csum[t] += __shfl_xor(csum[t], 16);
        csum[t] += __shfl_xor(csum[t], 32);
        csq[t] += __shfl_xor(csq[t], 16);
        csq[t] += __shfl_xor(csq[t], 32);
    }
    __syncthreads();
    float* red = (float*)Bh;
    if (q == 0) {
#pragma unroll
        for (int t = 0; t < 8; t++) {
            int col = n16 + 16 * t;
            red[wave * 128 + col] = csum[t];
            red[512 + wave * 128 + col] = csq[t];
        }
    }
    __syncthreads();
    if (tid < 128) {
        float s = 0.f, qq = 0.f;
#pragma unroll
        for (int w = 0; w < 4; w++) {
            s += red[w * 128 + tid];
            qq += red[512 + w * 128 + tid];
        }
        unsafeAtomicAdd(&sum_out[tid], s);
        unsafeAtomicAdd(&sq_out[tid], qq);
    }
}

// final: out = relu(scale2 * z2 + shift2), scale/shift from global sums
__global__ __launch_bounds__(256) void apply_k(const unsigned short* __restrict__ z2,
        const float* __restrict__ sum2, const float* __restrict__ sq2,
        const float* __restrict__ gamma, const float* __restrict__ beta,
        float* __restrict__ out, long long n8, float invN) {
    __shared__ float sc[128], sh[128];
    int tid = threadIdx.x;
    if (tid < 128) {
        float mean = sum2[tid] * invN;
        float var = fmaxf(sq2[tid] * invN - mean * mean, 0.f);
        float s = gamma[tid] * rsqrtf(var + 1e-5f);
        sc[tid] = s;
        sh[tid] = beta[tid] - mean * s;
    }
    __syncthreads();
    long long g = (long long)blockIdx.x * 256 + tid;
    if (g >= n8) return;
    uint4 u = ((const uint4*)z2)[g];
    int cb = (int)((g * 8) & 127);
    float4 s0 = *(const float4*)&sc[cb], s1 = *(const float4*)&sc[cb + 4];
    float4 t0 = *(const float4*)&sh[cb], t1 = *(const float4*)&sh[cb + 4];
    float4 o0, o1;
    o0.x = fmaxf(fmaf(bf2f(u.x & 0xFFFF), s0.x, t0.x), 0.f);
    o0.y = fmaxf(fmaf(bf2f(u.x >> 16), s0.y, t0.y), 0.f);
    o0.z = fmaxf(fmaf(bf2f(u.y & 0xFFFF), s0.z, t0.z), 0.f);
    o0.w = fmaxf(fmaf(bf2f(u.y >> 16), s0.w, t0.w), 0.f);
    o1.x = fmaxf(fmaf(bf2f(u.z & 0xFFFF), s1.x, t1.x), 0.f);
    o1.y = fmaxf(fmaf(bf2f(u.z >> 16), s1.y, t1.y), 0.f);
    o1.z = fmaxf(fmaf(bf2f(u.w & 0xFFFF), s1.z, t1.z), 0.f);
    o1.w = fmaxf(fmaf(bf2f(u.w >> 16), s1.w, t1.w), 0.f);
    ((float4*)out)[g * 2] = o0;
    ((float4*)out)[g * 2 + 1] = o1;
}

extern "C" void kernel_launch(void* const* d_in, const int* in_sizes, int n_in,
                              void* d_out, int out_size, void* d_ws, size_t ws_size,
                              hipStream_t stream) {
    const float* x   = (const float*)d_in[0];
    const int*   ei  = (const int*)d_in[1];
    const int*   ew  = (const int*)d_in[2];
    const float* hc  = (const float*)d_in[3];
    const float* W1  = (const float*)d_in[4];
    const float* b1  = (const float*)d_in[5];
    const float* g1  = (const float*)d_in[6];
    const float* be1 = (const float*)d_in[7];
    const float* W2  = (const float*)d_in[8];
    const float* b2  = (const float*)d_in[9];
    const float* g2  = (const float*)d_in[10];
    const float* be2 = (const float*)d_in[11];

    int N = in_sizes[0] / 128;
    int E = in_sizes[2];
    int K = in_sizes[3];
    int NB = (N + 255) / 256;
    size_t NF = (size_t)N * 128;
    long long n8 = (long long)(NF / 8);

    // workspace: h | xb(->z1 alias) | epay | cnt | s1 | bscan | bsum | seq |
    //            W splits | hwp | sums(512)
    unsigned short* h = (unsigned short*)d_ws;          // NF ushort (z2 aliases)
    unsigned short* xb = h + NF;                        // NF ushort
    unsigned short* z1 = xb;                            // alias: xb dead after gather
    unsigned short* z2 = h;                             // alias: h dead after gemm1
    int2* epay = (int2*)(xb + NF);                      // E int2
    int* cnt = (int*)(epay + E);                        // N
    int* s1 = cnt + N;                                  // N
    int* bscan = s1 + N;                                // 512
    int* bsum = bscan + 512;                            // 512
    int* seq = bsum + 512;                              // E
    unsigned short* w1h = (unsigned short*)(seq + E);   // 4 x 16384
    unsigned short* w1l = w1h + 16384;
    unsigned short* w2h = w1l + 16384;
    unsigned short* w2l = w2h + 16384;
    float* hwp = (float*)(w2l + 16384);                 // 8
    float* sums = hwp + 8;                              // 512: sum1|sq1|sum2|sq2
    float* sum1 = sums, *sq1 = sums + 128, *sum2 = sums + 256, *sq2 = sums + 384;

    float invN = 1.0f / (float)N;

    {
        int NX = (int)((n8 + 255) / 256);
        prep_k<<<3 + NB + NX, 256, 0, stream>>>(hc, hwp, sums, W1, W2,
            w1h, w1l, w2h, w2l, cnt, (const float4*)x, (uint4*)xb, N, K, NB, n8);
    }
    {
        int blocks = (E / 4 + 256) / 256;   // covers tail
        count_k<<<blocks, 256, 0, stream>>>(ei, cnt, seq, E);
    }
    scan1_k<<<NB, 256, 0, stream>>>(cnt, s1, bsum, N);
    scan2_k<<<1, 512, 0, stream>>>(bsum, bscan, NB);
    {
        int blocks = (E / 4 + 256) / 256;
        fill_k<<<blocks, 256, 0, stream>>>(ei, ei + E, ew, seq, s1, bscan, hwp, epay, E, K);
    }
    {
        long long tot = (long long)N * 64;
        gather_k<<<(int)((tot + 255) / 256), 256, 0, stream>>>(xb, epay, s1, bscan,
            cnt, h, N);
    }
    int gblocks = (N + 127) / 128;
    gemm_mfma_k<false><<<gblocks, 256, 0, stream>>>(h, w1h, w1l, b1,
        nullptr, nullptr, nullptr, nullptr, z1, sum1, sq1, N, invN);
    gemm_mfma_k<true><<<gblocks, 256, 0, stream>>>(z1, w2h, w2l, b2,
        sum1, sq1, g1, be1, z2, sum2, sq2, N, invN);
    apply_k<<<(int)((n8 + 255) / 256), 256, 0, stream>>>(z2, sum2, sq2, g2, be2,
        (float*)d_out, n8, invN);
}